// Round 5
// baseline (383.647 us; speedup 1.0000x reference)
//
#include <hip/hip_runtime.h>

// ---------- types & helpers ----------
typedef __attribute__((ext_vector_type(8))) short short8;
typedef __attribute__((ext_vector_type(4))) float f32x4;

#define MFMA16 __builtin_amdgcn_mfma_f32_16x16x32_bf16

#define GLOAD16(gp, lp) __builtin_amdgcn_global_load_lds(                      \
    (const __attribute__((address_space(1))) void*)(gp),                       \
    (__attribute__((address_space(3))) void*)(lp), 16, 0, 0)

__device__ __forceinline__ unsigned short f2bf(float f) {
  unsigned int u = __float_as_uint(f);
  unsigned int r = u + 0x7fffu + ((u >> 16) & 1u);
  return (unsigned short)(r >> 16);
}
__device__ __forceinline__ float bf2f(unsigned short h) {
  return __uint_as_float(((unsigned int)h) << 16);
}

// ---------- cast fp32 -> bf16 (vector4) ----------
__global__ __launch_bounds__(256) void cast_x_kernel(
    const float* __restrict__ in, unsigned short* __restrict__ out, int n4) {
  int i = blockIdx.x * 256 + threadIdx.x;
  if (i >= n4) return;
  float4 v = reinterpret_cast<const float4*>(in)[i];
  ushort4 o;
  o.x = f2bf(v.x); o.y = f2bf(v.y); o.z = f2bf(v.z); o.w = f2bf(v.w);
  reinterpret_cast<ushort4*>(out)[i] = o;
}

// ---------- transpose + cast fp32 -> bf16 : out[C][R] = in[R][C] ----------
__global__ __launch_bounds__(256) void tcast_f32_kernel(
    const float* __restrict__ in, unsigned short* __restrict__ out, int R, int C) {
  __shared__ float t[64][65];
  int c0 = blockIdx.x * 64, r0 = blockIdx.y * 64;
  int tx = threadIdx.x, ty = threadIdx.y;  // (64,4)
#pragma unroll
  for (int i = 0; i < 16; ++i)
    t[ty + 4 * i][tx] = in[(size_t)(r0 + ty + 4 * i) * C + c0 + tx];
  __syncthreads();
#pragma unroll
  for (int i = 0; i < 16; ++i)
    out[(size_t)(c0 + ty + 4 * i) * R + r0 + tx] = f2bf(t[tx][ty + 4 * i]);
}

// ---------- batched bf16 transpose : out[z][C][R] = in[z][R][C] ----------
__global__ __launch_bounds__(256) void t_bf16_kernel(
    const unsigned short* __restrict__ in, unsigned short* __restrict__ out, int R, int C) {
  __shared__ unsigned short t[64][66];
  size_t base = (size_t)blockIdx.z * (size_t)R * (size_t)C;
  int c0 = blockIdx.x * 64, r0 = blockIdx.y * 64;
  int tx = threadIdx.x, ty = threadIdx.y;  // (64,4)
#pragma unroll
  for (int i = 0; i < 16; ++i)
    t[ty + 4 * i][tx] = in[base + (size_t)(r0 + ty + 4 * i) * C + c0 + tx];
  __syncthreads();
#pragma unroll
  for (int i = 0; i < 16; ++i)
    out[base + (size_t)(c0 + ty + 4 * i) * R + r0 + tx] = t[tx][ty + 4 * i];
}

// ---------- 256x256 GEMM, BK=32, 4-buffer depth-3 prefetch pipeline ----------
// C[M,1024] = A[M,1024] @ W ([N][K] layout). 8 waves (2Mx4N), 128x64 out/wave.
// LDS = 4 buf x (A 16KB + B 16KB) = 128 KiB. Per tile: 4 load-issues/thread.
// Steady state: vmcnt(12) -> tiles t+1,t+2,t+3 in flight (~930cy latency cover).
// Swizzle: 16B-chunk' = chunk ^ (row&3) ^ ((row>>2)&3) (involution); source
// pre-swizzled, LDS linear, reads apply same XOR -> conflict-free b128 reads.
template <int OUTF>
__global__ __launch_bounds__(512) void gemm256_kernel(
    const unsigned short* __restrict__ A,
    const unsigned short* W0, const unsigned short* W1, const unsigned short* W2,
    const float* b0, const float* b1, const float* b2,
    void* o0, void* o1, void* o2) {
  constexpr int KD = 1024, ND = 1024, NT = KD / 32;
  const unsigned short* W = W0; const float* bias = b0; void* op = o0;
  if (blockIdx.z == 1) { W = W1; bias = b1; op = o1; }
  else if (blockIdx.z == 2) { W = W2; bias = b2; op = o2; }

  __shared__ unsigned short lsA[4][8192];
  __shared__ unsigned short lsB[4][8192];
  int tid = threadIdx.x;
  int w = tid >> 6, lane = tid & 63;
  int lo = lane & 15, hi = lane >> 4;
  int wr = w >> 2, wc = w & 3;
  int m0 = blockIdx.x * 256, n0 = blockIdx.y * 256;

  // staging: row = i*128 + tid/4, chunk slot = tid&3, source chunk pre-swizzled
  int srow = tid >> 2;
  int sx = ((tid >> 2) & 3) ^ ((tid >> 4) & 3);  // X(row), i*128 doesn't affect it
  int schunk = (tid & 3) ^ sx;
  const unsigned short* gA0 = A + (size_t)(m0 + srow) * KD + schunk * 8;
  const unsigned short* gB0 = W + (size_t)(n0 + srow) * KD + schunk * 8;

#define STAGE_TILE(tt, buf)                                                    \
  do {                                                                         \
    int kb_ = (tt) * 32;                                                       \
    GLOAD16(gA0 + kb_, &lsA[buf][w * 512]);                                    \
    GLOAD16(gA0 + (size_t)128 * KD + kb_, &lsA[buf][4096 + w * 512]);          \
    GLOAD16(gB0 + kb_, &lsB[buf][w * 512]);                                    \
    GLOAD16(gB0 + (size_t)128 * KD + kb_, &lsB[buf][4096 + w * 512]);          \
  } while (0)

  f32x4 acc[8][4];
#pragma unroll
  for (int m = 0; m < 8; ++m)
#pragma unroll
    for (int fn = 0; fn < 4; ++fn) acc[m][fn] = (f32x4){0.f, 0.f, 0.f, 0.f};

  // prologue: stage tiles 0,1,2
  STAGE_TILE(0, 0);
  STAGE_TILE(1, 1);
  STAGE_TILE(2, 2);

  for (int t = 0; t < NT; ++t) {
    int buf = t & 3;
    int rem = NT - 1 - t;
    if (rem >= 3) {
      STAGE_TILE(t + 3, (t + 3) & 3);
      __builtin_amdgcn_sched_barrier(0);
      asm volatile("s_waitcnt vmcnt(12)" ::: "memory");
    } else if (rem == 2) {
      __builtin_amdgcn_sched_barrier(0);
      asm volatile("s_waitcnt vmcnt(8)" ::: "memory");
    } else if (rem == 1) {
      __builtin_amdgcn_sched_barrier(0);
      asm volatile("s_waitcnt vmcnt(4)" ::: "memory");
    } else {
      __builtin_amdgcn_sched_barrier(0);
      asm volatile("s_waitcnt vmcnt(0)" ::: "memory");
    }
    __builtin_amdgcn_sched_barrier(0);
    __builtin_amdgcn_s_barrier();
    __builtin_amdgcn_sched_barrier(0);

    short8 bfr[4];
#pragma unroll
    for (int fn = 0; fn < 4; ++fn) {
      int col = wc * 64 + fn * 16 + lo;
      int cx = (col & 3) ^ ((col >> 2) & 3);
      bfr[fn] = *reinterpret_cast<const short8*>(&lsB[buf][col * 32 + (hi ^ cx) * 8]);
    }
    __builtin_amdgcn_s_setprio(1);
#pragma unroll
    for (int mp = 0; mp < 4; ++mp) {
      short8 afr[2];
#pragma unroll
      for (int mi = 0; mi < 2; ++mi) {
        int row = wr * 128 + mp * 32 + mi * 16 + lo;
        int rx = (row & 3) ^ ((row >> 2) & 3);
        afr[mi] = *reinterpret_cast<const short8*>(&lsA[buf][row * 32 + (hi ^ rx) * 8]);
      }
#pragma unroll
      for (int mi = 0; mi < 2; ++mi)
#pragma unroll
        for (int fn = 0; fn < 4; ++fn)
          acc[mp * 2 + mi][fn] = MFMA16(afr[mi], bfr[fn], acc[mp * 2 + mi][fn], 0, 0, 0);
    }
    __builtin_amdgcn_s_setprio(0);
    __builtin_amdgcn_sched_barrier(0);
    __builtin_amdgcn_s_barrier();  // reads of buf done -> free for reuse
    __builtin_amdgcn_sched_barrier(0);
  }
#undef STAGE_TILE

#pragma unroll
  for (int fn = 0; fn < 4; ++fn) {
    int col = n0 + wc * 64 + fn * 16 + lo;
    float bv = bias[col];
#pragma unroll
    for (int m = 0; m < 8; ++m)
#pragma unroll
      for (int j = 0; j < 4; ++j) {
        int row = m0 + wr * 128 + m * 16 + hi * 4 + j;
        float v = acc[m][fn][j] + bv;
        if (OUTF)
          reinterpret_cast<float*>(op)[(size_t)row * ND + col] = v;
        else
          reinterpret_cast<unsigned short*>(op)[(size_t)row * ND + col] = f2bf(v);
      }
  }
}

// ---------- fused featmap(k) + kv + ksum (split over N, S=8) ----------
__global__ __launch_bounds__(256) void kv_fused_kernel(
    const unsigned short* __restrict__ K, const unsigned short* __restrict__ PT,
    const unsigned short* __restrict__ VT,
    float* __restrict__ kvp, float* __restrict__ ksp) {
  __shared__ unsigned short kp[256 * 40];  // [f][n] transposed k' tile, stride 40
  int s = blockIdx.x, bh = blockIdx.y, b = bh >> 4, h = bh & 15;
  int tid = threadIdx.x, w = tid >> 6, lane = tid & 63;
  int lo = lane & 15, hi = lane >> 4;
  int f0w = w * 64;

  short8 pb[4][2];
#pragma unroll
  for (int fn = 0; fn < 4; ++fn) {
    int f = f0w + fn * 16 + lo;
    pb[fn][0] = *reinterpret_cast<const short8*>(PT + (size_t)f * 64 + hi * 8);
    pb[fn][1] = *reinterpret_cast<const short8*>(PT + (size_t)f * 64 + 32 + hi * 8);
  }
  const unsigned short* vbase[4];
#pragma unroll
  for (int fn = 0; fn < 4; ++fn)
    vbase[fn] = VT + (size_t)(bh * 64 + fn * 16 + lo) * 4096;

  f32x4 acck[4][4];
#pragma unroll
  for (int fm = 0; fm < 4; ++fm)
#pragma unroll
    for (int fn = 0; fn < 4; ++fn) acck[fm][fn] = (f32x4){0.f, 0.f, 0.f, 0.f};
  float ks[4] = {0.f, 0.f, 0.f, 0.f};

  for (int c = 0; c < 16; ++c) {
    int n0 = s * 512 + c * 32;
    const unsigned short* Ab = K + (size_t)(b * 4096 + n0) * 1024 + h * 64;
    short8 af[2][2];
    float dp[2] = {0.f, 0.f};
#pragma unroll
    for (int fm = 0; fm < 2; ++fm)
#pragma unroll
      for (int kt = 0; kt < 2; ++kt) {
        af[fm][kt] = *reinterpret_cast<const short8*>(
            Ab + (size_t)(fm * 16 + lo) * 1024 + kt * 32 + hi * 8);
#pragma unroll
        for (int j = 0; j < 8; ++j) {
          float qv = bf2f((unsigned short)af[fm][kt][j]);
          dp[fm] += qv * qv;
        }
      }
#pragma unroll
    for (int fm = 0; fm < 2; ++fm) {
      dp[fm] += __shfl_xor(dp[fm], 16);
      dp[fm] += __shfl_xor(dp[fm], 32);
    }
    f32x4 accf[2][4];
#pragma unroll
    for (int fm = 0; fm < 2; ++fm)
#pragma unroll
      for (int fn = 0; fn < 4; ++fn) accf[fm][fn] = (f32x4){0.f, 0.f, 0.f, 0.f};
#pragma unroll
    for (int fn = 0; fn < 4; ++fn) {
      accf[0][fn] = MFMA16(af[0][0], pb[fn][0], accf[0][fn], 0, 0, 0);
      accf[0][fn] = MFMA16(af[0][1], pb[fn][1], accf[0][fn], 0, 0, 0);
      accf[1][fn] = MFMA16(af[1][0], pb[fn][0], accf[1][fn], 0, 0, 0);
      accf[1][fn] = MFMA16(af[1][1], pb[fn][1], accf[1][fn], 0, 0, 0);
    }
#pragma unroll
    for (int fm = 0; fm < 2; ++fm)
#pragma unroll
      for (int fn = 0; fn < 4; ++fn)
#pragma unroll
        for (int j = 0; j < 4; ++j) {
          float dg = __shfl(dp[fm], hi * 4 + j);
          float v = 0.125f *
                    (__expf(0.35355339059327373f * accf[fm][fn][j] - 0.0625f * dg) + 1e-6f);
          ks[fn] += v;
          kp[(f0w + fn * 16 + lo) * 40 + fm * 16 + hi * 4 + j] = f2bf(v);
        }
    short8 a2[4], b2[4];
#pragma unroll
    for (int fm = 0; fm < 4; ++fm)
      a2[fm] = *reinterpret_cast<const short8*>(&kp[(f0w + fm * 16 + lo) * 40 + hi * 8]);
#pragma unroll
    for (int fn = 0; fn < 4; ++fn)
      b2[fn] = *reinterpret_cast<const short8*>(vbase[fn] + n0 + hi * 8);
#pragma unroll
    for (int fm = 0; fm < 4; ++fm)
#pragma unroll
      for (int fn = 0; fn < 4; ++fn)
        acck[fm][fn] = MFMA16(a2[fm], b2[fn], acck[fm][fn], 0, 0, 0);
  }
#pragma unroll
  for (int fn = 0; fn < 4; ++fn) {
    float v = ks[fn];
    v += __shfl_xor(v, 16);
    v += __shfl_xor(v, 32);
    if (hi == 0)
      ksp[(size_t)(s * 64 + bh) * 256 + f0w + fn * 16 + lo] = v;
  }
#pragma unroll
  for (int fm = 0; fm < 4; ++fm)
#pragma unroll
    for (int fn = 0; fn < 4; ++fn)
#pragma unroll
      for (int j = 0; j < 4; ++j)
        kvp[((size_t)(s * 64 + bh) * 256 + f0w + fm * 16 + hi * 4 + j) * 64 + fn * 16 + lo] =
            acck[fm][fn][j];
}

// ---------- reduce split parts -> kvT bf16 [bh][64 d][256 f], ksum fp32 [bh][256] ----------
__global__ __launch_bounds__(256) void kvred_kernel(
    const float* __restrict__ kvp, const float* __restrict__ ksp,
    unsigned short* __restrict__ kvT, float* __restrict__ ksum) {
  int bh = blockIdx.x, tid = threadIdx.x;
  for (int i = tid; i < 64 * 256; i += 256) {
    int f = i >> 6, d = i & 63;
    float sum = 0.f;
#pragma unroll
    for (int s = 0; s < 8; ++s)
      sum += kvp[((size_t)(s * 64 + bh) * 256 + f) * 64 + d];
    kvT[(size_t)(bh * 64 + d) * 256 + f] = f2bf(sum);
  }
  {
    float t = 0.f;
#pragma unroll
    for (int s = 0; s < 8; ++s) t += ksp[(size_t)(s * 64 + bh) * 256 + tid];
    ksum[bh * 256 + tid] = t;
  }
}

// ---------- fused featmap(q) + qkv + norm ----------
__global__ __launch_bounds__(256) void qkv_fused_kernel(
    const unsigned short* __restrict__ Q, const unsigned short* __restrict__ PT,
    const unsigned short* __restrict__ KVT, const float* __restrict__ KSUM,
    unsigned short* __restrict__ Y) {
  __shared__ unsigned short qp[128 * 256];  // XOR-swizzled q' tile
  int bh = blockIdx.y, b = bh >> 4, h = bh & 15;
  int t0 = blockIdx.x * 128;
  int tid = threadIdx.x, w = tid >> 6, lane = tid & 63;
  int lo = lane & 15, hi = lane >> 4;
  int r0 = w * 32;
  const unsigned short* Ab = Q + (size_t)(b * 4096 + t0 + r0) * 1024 + h * 64;

  float ksr[16];
#pragma unroll
  for (int fn = 0; fn < 16; ++fn) ksr[fn] = KSUM[bh * 256 + fn * 16 + lo];

  short8 af[2][2];
  float dp[2] = {0.f, 0.f};
#pragma unroll
  for (int fm = 0; fm < 2; ++fm)
#pragma unroll
    for (int kt = 0; kt < 2; ++kt) {
      af[fm][kt] = *reinterpret_cast<const short8*>(
          Ab + (size_t)(fm * 16 + lo) * 1024 + kt * 32 + hi * 8);
#pragma unroll
      for (int j = 0; j < 8; ++j) {
        float qv = bf2f((unsigned short)af[fm][kt][j]);
        dp[fm] += qv * qv;
      }
    }
#pragma unroll
  for (int fm = 0; fm < 2; ++fm) {
    dp[fm] += __shfl_xor(dp[fm], 16);
    dp[fm] += __shfl_xor(dp[fm], 32);
  }

  float np[2][4] = {{0.f, 0.f, 0.f, 0.f}, {0.f, 0.f, 0.f, 0.f}};
#pragma unroll
  for (int hf = 0; hf < 2; ++hf) {
    f32x4 accf[2][8];
#pragma unroll
    for (int fm = 0; fm < 2; ++fm)
#pragma unroll
      for (int fn = 0; fn < 8; ++fn) accf[fm][fn] = (f32x4){0.f, 0.f, 0.f, 0.f};
#pragma unroll
    for (int fn = 0; fn < 8; ++fn) {
      int f = (hf * 8 + fn) * 16 + lo;
      short8 pb0 = *reinterpret_cast<const short8*>(PT + (size_t)f * 64 + hi * 8);
      short8 pb1 = *reinterpret_cast<const short8*>(PT + (size_t)f * 64 + 32 + hi * 8);
      accf[0][fn] = MFMA16(af[0][0], pb0, accf[0][fn], 0, 0, 0);
      accf[0][fn] = MFMA16(af[0][1], pb1, accf[0][fn], 0, 0, 0);
      accf[1][fn] = MFMA16(af[1][0], pb0, accf[1][fn], 0, 0, 0);
      accf[1][fn] = MFMA16(af[1][1], pb1, accf[1][fn], 0, 0, 0);
    }
#pragma unroll
    for (int fm = 0; fm < 2; ++fm)
#pragma unroll
      for (int fn = 0; fn < 8; ++fn)
#pragma unroll
        for (int j = 0; j < 4; ++j) {
          float dg = __shfl(dp[fm], hi * 4 + j);
          float v = 0.125f *
                    (__expf(0.35355339059327373f * accf[fm][fn][j] - 0.0625f * dg) + 1e-6f);
          np[fm][j] += v * ksr[hf * 8 + fn];
          int row = r0 + fm * 16 + hi * 4 + j;
          int f = (hf * 8 + fn) * 16 + lo;
          int byt = (row * 512 + f * 2) ^ ((row & 7) << 4);
          *reinterpret_cast<unsigned short*>(reinterpret_cast<char*>(qp) + byt) = f2bf(v);
        }
  }
#pragma unroll
  for (int fm = 0; fm < 2; ++fm)
#pragma unroll
    for (int j = 0; j < 4; ++j) {
      np[fm][j] += __shfl_xor(np[fm][j], 1);
      np[fm][j] += __shfl_xor(np[fm][j], 2);
      np[fm][j] += __shfl_xor(np[fm][j], 4);
      np[fm][j] += __shfl_xor(np[fm][j], 8);
    }
  f32x4 acco[2][4];
#pragma unroll
  for (int fm = 0; fm < 2; ++fm)
#pragma unroll
    for (int fn = 0; fn < 4; ++fn) acco[fm][fn] = (f32x4){0.f, 0.f, 0.f, 0.f};
#pragma unroll
  for (int kt2 = 0; kt2 < 8; ++kt2) {
    short8 a2[2], b2[4];
#pragma unroll
    for (int fm = 0; fm < 2; ++fm) {
      int row = r0 + fm * 16 + lo;
      int byt = (row * 512 + kt2 * 64 + hi * 16) ^ ((row & 7) << 4);
      a2[fm] = *reinterpret_cast<const short8*>(reinterpret_cast<char*>(qp) + byt);
    }
#pragma unroll
    for (int fn = 0; fn < 4; ++fn)
      b2[fn] = *reinterpret_cast<const short8*>(
          KVT + (size_t)(bh * 64 + fn * 16 + lo) * 256 + kt2 * 32 + hi * 8);
#pragma unroll
    for (int fm = 0; fm < 2; ++fm)
#pragma unroll
      for (int fn = 0; fn < 4; ++fn)
        acco[fm][fn] = MFMA16(a2[fm], b2[fn], acco[fm][fn], 0, 0, 0);
  }
#pragma unroll
  for (int fm = 0; fm < 2; ++fm)
#pragma unroll
    for (int j = 0; j < 4; ++j) {
      float nv = np[fm][j] + 1e-6f;
      int row = b * 4096 + t0 + r0 + fm * 16 + hi * 4 + j;
#pragma unroll
      for (int fn = 0; fn < 4; ++fn)
        Y[(size_t)row * 1024 + h * 64 + fn * 16 + lo] = f2bf(acco[fm][fn][j] / nv);
    }
}

// ---------- host ----------
extern "C" void kernel_launch(void* const* d_in, const int* in_sizes, int n_in,
                              void* d_out, int out_size, void* d_ws, size_t ws_size,
                              hipStream_t stream) {
  (void)in_sizes; (void)n_in; (void)out_size; (void)ws_size;
  const float* x    = (const float*)d_in[0];
  const float* Wq   = (const float*)d_in[2];
  const float* bq   = (const float*)d_in[3];
  const float* Wk   = (const float*)d_in[4];
  const float* bk   = (const float*)d_in[5];
  const float* Wv   = (const float*)d_in[6];
  const float* bv   = (const float*)d_in[7];
  const float* Wo   = (const float*)d_in[8];
  const float* bo   = (const float*)d_in[9];
  const float* proj = (const float*)d_in[10];
  float* out = (float*)d_out;

  constexpr size_t SZ_XB = (size_t)16384 * 1024 * 2;  // 32 MiB
  constexpr size_t SZ_W  = (size_t)1024 * 1024 * 2;   // 2 MiB
  constexpr size_t SZ_PT = (size_t)256 * 64 * 2;      // 32 KiB

  char* p = (char*)d_ws;
  size_t off = 0;
  char* a_xb  = p + off; off += SZ_XB;
  char* a_WqT = p + off; off += SZ_W;
  char* a_WkT = p + off; off += SZ_W;
  char* a_WvT = p + off; off += SZ_W;
  char* a_WoT = p + off; off += SZ_W;
  char* a_pT  = p + off; off += SZ_PT;
  char* a_qb  = p + off; off += SZ_XB;
  char* a_kb  = p + off; off += SZ_XB;
  char* a_ksp  = p + off; off += (size_t)8 * 64 * 256 * 4;       // 512 KiB
  char* a_kvT  = p + off; off += (size_t)64 * 64 * 256 * 2;      // 2 MiB
  char* a_ksum = p + off; off += (size_t)64 * 256 * 4;           // 64 KiB

  // kv parts alias xb (xb dead after QKV GEMM): 8*64*256*64*4 = 32 MiB exactly
  char* a_kvp = a_xb;
  // y aliases kb (kb dead after kv_fused)
  char* a_y = a_kb;
  // v and vT live in d_out (64 MiB exactly; fully overwritten by final GEMM)
  char* a_vb = (char*)d_out;
  char* a_vT = (char*)d_out + SZ_XB;

  dim3 tb(64, 4);

  cast_x_kernel<<<16384, 256, 0, stream>>>(x, (unsigned short*)a_xb, 16384 * 1024 / 4);
  tcast_f32_kernel<<<dim3(16, 16), tb, 0, stream>>>(Wq, (unsigned short*)a_WqT, 1024, 1024);
  tcast_f32_kernel<<<dim3(16, 16), tb, 0, stream>>>(Wk, (unsigned short*)a_WkT, 1024, 1024);
  tcast_f32_kernel<<<dim3(16, 16), tb, 0, stream>>>(Wv, (unsigned short*)a_WvT, 1024, 1024);
  tcast_f32_kernel<<<dim3(16, 16), tb, 0, stream>>>(Wo, (unsigned short*)a_WoT, 1024, 1024);
  tcast_f32_kernel<<<dim3(4, 1), tb, 0, stream>>>(proj, (unsigned short*)a_pT, 64, 256);

  gemm256_kernel<0><<<dim3(64, 4, 3), 512, 0, stream>>>(
      (unsigned short*)a_xb,
      (unsigned short*)a_WqT, (unsigned short*)a_WkT, (unsigned short*)a_WvT,
      bq, bk, bv, a_qb, a_kb, a_vb);

  t_bf16_kernel<<<dim3(16, 64, 4), tb, 0, stream>>>(
      (unsigned short*)a_vb, (unsigned short*)a_vT, 4096, 1024);

  kv_fused_kernel<<<dim3(8, 64), 256, 0, stream>>>(
      (unsigned short*)a_kb, (unsigned short*)a_pT, (unsigned short*)a_vT,
      (float*)a_kvp, (float*)a_ksp);
  kvred_kernel<<<64, 256, 0, stream>>>(
      (float*)a_kvp, (float*)a_ksp, (unsigned short*)a_kvT, (float*)a_ksum);

  qkv_fused_kernel<<<dim3(32, 64), 256, 0, stream>>>(
      (unsigned short*)a_qb, (unsigned short*)a_pT, (unsigned short*)a_kvT,
      (float*)a_ksum, (unsigned short*)a_y);

  gemm256_kernel<1><<<dim3(64, 4, 1), 512, 0, stream>>>(
      (unsigned short*)a_y,
      (unsigned short*)a_WoT, nullptr, nullptr,
      bo, nullptr, nullptr, out, nullptr, nullptr);
}

// Round 6
// 370.442 us; speedup vs baseline: 1.0356x; 1.0356x over previous
//
#include <hip/hip_runtime.h>

// ---------- types & helpers ----------
typedef __attribute__((ext_vector_type(8))) short short8;
typedef __attribute__((ext_vector_type(4))) float f32x4;

#define MFMA16 __builtin_amdgcn_mfma_f32_16x16x32_bf16

#define GLOAD16(gp, lp) __builtin_amdgcn_global_load_lds(                      \
    (const __attribute__((address_space(1))) void*)(gp),                       \
    (__attribute__((address_space(3))) void*)(lp), 16, 0, 0)

__device__ __forceinline__ unsigned short f2bf(float f) {
  unsigned int u = __float_as_uint(f);
  unsigned int r = u + 0x7fffu + ((u >> 16) & 1u);
  return (unsigned short)(r >> 16);
}
__device__ __forceinline__ float bf2f(unsigned short h) {
  return __uint_as_float(((unsigned int)h) << 16);
}

// ---------- cast fp32 -> bf16 (vector4) ----------
__global__ __launch_bounds__(256) void cast_x_kernel(
    const float* __restrict__ in, unsigned short* __restrict__ out, int n4) {
  int i = blockIdx.x * 256 + threadIdx.x;
  if (i >= n4) return;
  float4 v = reinterpret_cast<const float4*>(in)[i];
  ushort4 o;
  o.x = f2bf(v.x); o.y = f2bf(v.y); o.z = f2bf(v.z); o.w = f2bf(v.w);
  reinterpret_cast<ushort4*>(out)[i] = o;
}

// ---------- transpose + cast fp32 -> bf16 : out[C][R] = in[R][C] ----------
__global__ __launch_bounds__(256) void tcast_f32_kernel(
    const float* __restrict__ in, unsigned short* __restrict__ out, int R, int C) {
  __shared__ float t[64][65];
  int c0 = blockIdx.x * 64, r0 = blockIdx.y * 64;
  int tx = threadIdx.x, ty = threadIdx.y;  // (64,4)
#pragma unroll
  for (int i = 0; i < 16; ++i)
    t[ty + 4 * i][tx] = in[(size_t)(r0 + ty + 4 * i) * C + c0 + tx];
  __syncthreads();
#pragma unroll
  for (int i = 0; i < 16; ++i)
    out[(size_t)(c0 + ty + 4 * i) * R + r0 + tx] = f2bf(t[tx][ty + 4 * i]);
}

// ---------- batched bf16 transpose : out[z][C][R] = in[z][R][C] ----------
__global__ __launch_bounds__(256) void t_bf16_kernel(
    const unsigned short* __restrict__ in, unsigned short* __restrict__ out, int R, int C) {
  __shared__ unsigned short t[64][66];
  size_t base = (size_t)blockIdx.z * (size_t)R * (size_t)C;
  int c0 = blockIdx.x * 64, r0 = blockIdx.y * 64;
  int tx = threadIdx.x, ty = threadIdx.y;  // (64,4)
#pragma unroll
  for (int i = 0; i < 16; ++i)
    t[ty + 4 * i][tx] = in[base + (size_t)(r0 + ty + 4 * i) * C + c0 + tx];
  __syncthreads();
#pragma unroll
  for (int i = 0; i < 16; ++i)
    out[base + (size_t)(c0 + ty + 4 * i) * R + r0 + tx] = t[tx][ty + 4 * i];
}

// ---------- 256x256 GEMM, BK=64, 8-phase-style interleaved pipeline ----------
// C[M,1024] = A[M,1024] @ W ([N][K]). 8 waves (2Mx4N), 128x64 out/wave.
// LDS 128KiB: [buf][ks-half][256 rows x 32 elem(64B)]. Per K-tile: 4 phases of
// 16 MFMA; each phase stages ONE operand-half of tile t+1 (2 gloads/thread).
// Counted vmcnt(6) at phases 0/2 retires exactly the 2 halves that phase reads
// (FIFO order a0,b0,a1,b1); never drains to 0 in the main loop.
// Swizzle: 16B chunk c at LDS slot holds source chunk c^((row>>1)&3); staged
// via pre-swizzled global source (linear LDS dest), read with the same XOR ->
// conflict-free ds_read_b128 (8 granules/128B wrap, uniform).
template <int OUTF>
__global__ __launch_bounds__(512) void gemm256_kernel(
    const unsigned short* __restrict__ A,
    const unsigned short* W0, const unsigned short* W1, const unsigned short* W2,
    const float* b0, const float* b1, const float* b2,
    void* o0, void* o1, void* o2) {
  constexpr int KD = 1024, ND = 1024, NT = KD / 64;
  const unsigned short* W = W0; const float* bias = b0; void* op = o0;
  if (blockIdx.z == 1) { W = W1; bias = b1; op = o1; }
  else if (blockIdx.z == 2) { W = W2; bias = b2; op = o2; }

  __shared__ unsigned short lsA[2][2][8192];  // [buf][ks][256r x 32e]
  __shared__ unsigned short lsB[2][2][8192];
  int tid = threadIdx.x;
  int w = tid >> 6, lane = tid & 63;
  int lo = lane & 15, hi = lane >> 4;
  int wr = w >> 2, wc = w & 3;
  int m0 = blockIdx.x * 256, n0 = blockIdx.y * 256;
  int rx = (lo >> 1) & 3;  // read-side chunk XOR

  // staging: 1KB block bi = w + g*8 covers rows bi*16..+15 of a half;
  // lane -> row = bi*16 + (lane>>2), LDS chunk = lane&3,
  // source chunk = (lane&3) ^ ((row>>1)&3) = (lane&3) ^ ((lane>>3)&3).
  int srow = w * 16 + (lane >> 2);
  int sch = (lane & 3) ^ ((lane >> 3) & 3);
  const unsigned short* gA = A + (size_t)(m0 + srow) * KD + sch * 8;
  const unsigned short* gB = W + (size_t)(n0 + srow) * KD + sch * 8;

#define STAGE_HALF(dst, gp, koff)                                              \
  do {                                                                         \
    GLOAD16((gp) + (koff), &(dst)[w * 512]);                                   \
    GLOAD16((gp) + (size_t)128 * KD + (koff), &(dst)[w * 512 + 4096]);         \
  } while (0)

  f32x4 acc[8][4];
#pragma unroll
  for (int m = 0; m < 8; ++m)
#pragma unroll
    for (int fn = 0; fn < 4; ++fn) acc[m][fn] = (f32x4){0.f, 0.f, 0.f, 0.f};

  // prologue: tile 0, halves in FIFO order a0,b0,a1,b1
  STAGE_HALF(lsA[0][0], gA, 0);
  STAGE_HALF(lsB[0][0], gB, 0);
  STAGE_HALF(lsA[0][1], gA, 32);
  STAGE_HALF(lsB[0][1], gB, 32);

  for (int t = 0; t < NT; ++t) {
    int p = t & 1, q = p ^ 1;
    int kn = (t + 1) * 64;
    bool more = (t < NT - 1);
    short8 bf[4], afr[4];

    // ---- phase 0: ks=0, m-group 0 (+B ks0 reads) ----
    if (more) STAGE_HALF(lsA[q][0], gA, kn);
    __builtin_amdgcn_sched_barrier(0);
    if (more) asm volatile("s_waitcnt vmcnt(6)" ::: "memory");
    else      asm volatile("s_waitcnt vmcnt(4)" ::: "memory");
    __builtin_amdgcn_sched_barrier(0);
    __builtin_amdgcn_s_barrier();
#pragma unroll
    for (int fn = 0; fn < 4; ++fn)
      bf[fn] = *reinterpret_cast<const short8*>(
          &lsB[p][0][(wc * 64 + fn * 16 + lo) * 32 + (hi ^ rx) * 8]);
#pragma unroll
    for (int i = 0; i < 4; ++i)
      afr[i] = *reinterpret_cast<const short8*>(
          &lsA[p][0][(wr * 128 + i * 16 + lo) * 32 + (hi ^ rx) * 8]);
    asm volatile("s_waitcnt lgkmcnt(0)" ::: "memory");
    __builtin_amdgcn_sched_barrier(0);
    __builtin_amdgcn_s_setprio(1);
#pragma unroll
    for (int i = 0; i < 4; ++i)
#pragma unroll
      for (int fn = 0; fn < 4; ++fn)
        acc[i][fn] = MFMA16(afr[i], bf[fn], acc[i][fn], 0, 0, 0);
    __builtin_amdgcn_s_setprio(0);
    __builtin_amdgcn_sched_barrier(0);
    __builtin_amdgcn_s_barrier();

    // ---- phase 1: ks=0, m-group 1 (B reused from regs) ----
    if (more) STAGE_HALF(lsB[q][0], gB, kn);
    __builtin_amdgcn_sched_barrier(0);
    __builtin_amdgcn_s_barrier();
#pragma unroll
    for (int i = 0; i < 4; ++i)
      afr[i] = *reinterpret_cast<const short8*>(
          &lsA[p][0][(wr * 128 + 64 + i * 16 + lo) * 32 + (hi ^ rx) * 8]);
    asm volatile("s_waitcnt lgkmcnt(0)" ::: "memory");
    __builtin_amdgcn_sched_barrier(0);
    __builtin_amdgcn_s_setprio(1);
#pragma unroll
    for (int i = 0; i < 4; ++i)
#pragma unroll
      for (int fn = 0; fn < 4; ++fn)
        acc[4 + i][fn] = MFMA16(afr[i], bf[fn], acc[4 + i][fn], 0, 0, 0);
    __builtin_amdgcn_s_setprio(0);
    __builtin_amdgcn_sched_barrier(0);
    __builtin_amdgcn_s_barrier();

    // ---- phase 2: ks=1, m-group 0 (+B ks1 reads) ----
    if (more) STAGE_HALF(lsA[q][1], gA, kn + 32);
    __builtin_amdgcn_sched_barrier(0);
    if (more) asm volatile("s_waitcnt vmcnt(6)" ::: "memory");
    else      asm volatile("s_waitcnt vmcnt(0)" ::: "memory");
    __builtin_amdgcn_sched_barrier(0);
    __builtin_amdgcn_s_barrier();
#pragma unroll
    for (int fn = 0; fn < 4; ++fn)
      bf[fn] = *reinterpret_cast<const short8*>(
          &lsB[p][1][(wc * 64 + fn * 16 + lo) * 32 + (hi ^ rx) * 8]);
#pragma unroll
    for (int i = 0; i < 4; ++i)
      afr[i] = *reinterpret_cast<const short8*>(
          &lsA[p][1][(wr * 128 + i * 16 + lo) * 32 + (hi ^ rx) * 8]);
    asm volatile("s_waitcnt lgkmcnt(0)" ::: "memory");
    __builtin_amdgcn_sched_barrier(0);
    __builtin_amdgcn_s_setprio(1);
#pragma unroll
    for (int i = 0; i < 4; ++i)
#pragma unroll
      for (int fn = 0; fn < 4; ++fn)
        acc[i][fn] = MFMA16(afr[i], bf[fn], acc[i][fn], 0, 0, 0);
    __builtin_amdgcn_s_setprio(0);
    __builtin_amdgcn_sched_barrier(0);
    __builtin_amdgcn_s_barrier();

    // ---- phase 3: ks=1, m-group 1 ----
    if (more) STAGE_HALF(lsB[q][1], gB, kn + 32);
    __builtin_amdgcn_sched_barrier(0);
    __builtin_amdgcn_s_barrier();
#pragma unroll
    for (int i = 0; i < 4; ++i)
      afr[i] = *reinterpret_cast<const short8*>(
          &lsA[p][1][(wr * 128 + 64 + i * 16 + lo) * 32 + (hi ^ rx) * 8]);
    asm volatile("s_waitcnt lgkmcnt(0)" ::: "memory");
    __builtin_amdgcn_sched_barrier(0);
    __builtin_amdgcn_s_setprio(1);
#pragma unroll
    for (int i = 0; i < 4; ++i)
#pragma unroll
      for (int fn = 0; fn < 4; ++fn)
        acc[4 + i][fn] = MFMA16(afr[i], bf[fn], acc[4 + i][fn], 0, 0, 0);
    __builtin_amdgcn_s_setprio(0);
    __builtin_amdgcn_sched_barrier(0);
    __builtin_amdgcn_s_barrier();
  }
#undef STAGE_HALF

#pragma unroll
  for (int fn = 0; fn < 4; ++fn) {
    int col = n0 + wc * 64 + fn * 16 + lo;
    float bv = bias[col];
#pragma unroll
    for (int m = 0; m < 8; ++m)
#pragma unroll
      for (int j = 0; j < 4; ++j) {
        int row = m0 + wr * 128 + m * 16 + hi * 4 + j;
        float v = acc[m][fn][j] + bv;
        if (OUTF)
          reinterpret_cast<float*>(op)[(size_t)row * ND + col] = v;
        else
          reinterpret_cast<unsigned short*>(op)[(size_t)row * ND + col] = f2bf(v);
      }
  }
}

// ---------- fused featmap(k) + kv + ksum (split over N, S=8) ----------
__global__ __launch_bounds__(256) void kv_fused_kernel(
    const unsigned short* __restrict__ K, const unsigned short* __restrict__ PT,
    const unsigned short* __restrict__ VT,
    float* __restrict__ kvp, float* __restrict__ ksp) {
  __shared__ unsigned short kp[256 * 40];  // [f][n] transposed k' tile, stride 40
  int s = blockIdx.x, bh = blockIdx.y, b = bh >> 4, h = bh & 15;
  int tid = threadIdx.x, w = tid >> 6, lane = tid & 63;
  int lo = lane & 15, hi = lane >> 4;
  int f0w = w * 64;

  short8 pb[4][2];
#pragma unroll
  for (int fn = 0; fn < 4; ++fn) {
    int f = f0w + fn * 16 + lo;
    pb[fn][0] = *reinterpret_cast<const short8*>(PT + (size_t)f * 64 + hi * 8);
    pb[fn][1] = *reinterpret_cast<const short8*>(PT + (size_t)f * 64 + 32 + hi * 8);
  }
  const unsigned short* vbase[4];
#pragma unroll
  for (int fn = 0; fn < 4; ++fn)
    vbase[fn] = VT + (size_t)(bh * 64 + fn * 16 + lo) * 4096;

  f32x4 acck[4][4];
#pragma unroll
  for (int fm = 0; fm < 4; ++fm)
#pragma unroll
    for (int fn = 0; fn < 4; ++fn) acck[fm][fn] = (f32x4){0.f, 0.f, 0.f, 0.f};
  float ks[4] = {0.f, 0.f, 0.f, 0.f};

  for (int c = 0; c < 16; ++c) {
    int n0 = s * 512 + c * 32;
    const unsigned short* Ab = K + (size_t)(b * 4096 + n0) * 1024 + h * 64;
    short8 af[2][2];
    float dp[2] = {0.f, 0.f};
#pragma unroll
    for (int fm = 0; fm < 2; ++fm)
#pragma unroll
      for (int kt = 0; kt < 2; ++kt) {
        af[fm][kt] = *reinterpret_cast<const short8*>(
            Ab + (size_t)(fm * 16 + lo) * 1024 + kt * 32 + hi * 8);
#pragma unroll
        for (int j = 0; j < 8; ++j) {
          float qv = bf2f((unsigned short)af[fm][kt][j]);
          dp[fm] += qv * qv;
        }
      }
#pragma unroll
    for (int fm = 0; fm < 2; ++fm) {
      dp[fm] += __shfl_xor(dp[fm], 16);
      dp[fm] += __shfl_xor(dp[fm], 32);
    }
    f32x4 accf[2][4];
#pragma unroll
    for (int fm = 0; fm < 2; ++fm)
#pragma unroll
      for (int fn = 0; fn < 4; ++fn) accf[fm][fn] = (f32x4){0.f, 0.f, 0.f, 0.f};
#pragma unroll
    for (int fn = 0; fn < 4; ++fn) {
      accf[0][fn] = MFMA16(af[0][0], pb[fn][0], accf[0][fn], 0, 0, 0);
      accf[0][fn] = MFMA16(af[0][1], pb[fn][1], accf[0][fn], 0, 0, 0);
      accf[1][fn] = MFMA16(af[1][0], pb[fn][0], accf[1][fn], 0, 0, 0);
      accf[1][fn] = MFMA16(af[1][1], pb[fn][1], accf[1][fn], 0, 0, 0);
    }
#pragma unroll
    for (int fm = 0; fm < 2; ++fm)
#pragma unroll
      for (int fn = 0; fn < 4; ++fn)
#pragma unroll
        for (int j = 0; j < 4; ++j) {
          float dg = __shfl(dp[fm], hi * 4 + j);
          float v = 0.125f *
                    (__expf(0.35355339059327373f * accf[fm][fn][j] - 0.0625f * dg) + 1e-6f);
          ks[fn] += v;
          kp[(f0w + fn * 16 + lo) * 40 + fm * 16 + hi * 4 + j] = f2bf(v);
        }
    short8 a2[4], b2[4];
#pragma unroll
    for (int fm = 0; fm < 4; ++fm)
      a2[fm] = *reinterpret_cast<const short8*>(&kp[(f0w + fm * 16 + lo) * 40 + hi * 8]);
#pragma unroll
    for (int fn = 0; fn < 4; ++fn)
      b2[fn] = *reinterpret_cast<const short8*>(vbase[fn] + n0 + hi * 8);
#pragma unroll
    for (int fm = 0; fm < 4; ++fm)
#pragma unroll
      for (int fn = 0; fn < 4; ++fn)
        acck[fm][fn] = MFMA16(a2[fm], b2[fn], acck[fm][fn], 0, 0, 0);
  }
#pragma unroll
  for (int fn = 0; fn < 4; ++fn) {
    float v = ks[fn];
    v += __shfl_xor(v, 16);
    v += __shfl_xor(v, 32);
    if (hi == 0)
      ksp[(size_t)(s * 64 + bh) * 256 + f0w + fn * 16 + lo] = v;
  }
#pragma unroll
  for (int fm = 0; fm < 4; ++fm)
#pragma unroll
    for (int fn = 0; fn < 4; ++fn)
#pragma unroll
      for (int j = 0; j < 4; ++j)
        kvp[((size_t)(s * 64 + bh) * 256 + f0w + fm * 16 + hi * 4 + j) * 64 + fn * 16 + lo] =
            acck[fm][fn][j];
}

// ---------- reduce split parts -> kvT bf16 [bh][64 d][256 f], ksum fp32 [bh][256] ----------
__global__ __launch_bounds__(256) void kvred_kernel(
    const float* __restrict__ kvp, const float* __restrict__ ksp,
    unsigned short* __restrict__ kvT, float* __restrict__ ksum) {
  int bh = blockIdx.x, tid = threadIdx.x;
  for (int i = tid; i < 64 * 256; i += 256) {
    int f = i >> 6, d = i & 63;
    float sum = 0.f;
#pragma unroll
    for (int s = 0; s < 8; ++s)
      sum += kvp[((size_t)(s * 64 + bh) * 256 + f) * 64 + d];
    kvT[(size_t)(bh * 64 + d) * 256 + f] = f2bf(sum);
  }
  {
    float t = 0.f;
#pragma unroll
    for (int s = 0; s < 8; ++s) t += ksp[(size_t)(s * 64 + bh) * 256 + tid];
    ksum[bh * 256 + tid] = t;
  }
}

// ---------- fused featmap(q) + qkv + norm ----------
__global__ __launch_bounds__(256) void qkv_fused_kernel(
    const unsigned short* __restrict__ Q, const unsigned short* __restrict__ PT,
    const unsigned short* __restrict__ KVT, const float* __restrict__ KSUM,
    unsigned short* __restrict__ Y) {
  __shared__ unsigned short qp[128 * 256];  // XOR-swizzled q' tile
  int bh = blockIdx.y, b = bh >> 4, h = bh & 15;
  int t0 = blockIdx.x * 128;
  int tid = threadIdx.x, w = tid >> 6, lane = tid & 63;
  int lo = lane & 15, hi = lane >> 4;
  int r0 = w * 32;
  const unsigned short* Ab = Q + (size_t)(b * 4096 + t0 + r0) * 1024 + h * 64;

  float ksr[16];
#pragma unroll
  for (int fn = 0; fn < 16; ++fn) ksr[fn] = KSUM[bh * 256 + fn * 16 + lo];

  short8 af[2][2];
  float dp[2] = {0.f, 0.f};
#pragma unroll
  for (int fm = 0; fm < 2; ++fm)
#pragma unroll
    for (int kt = 0; kt < 2; ++kt) {
      af[fm][kt] = *reinterpret_cast<const short8*>(
          Ab + (size_t)(fm * 16 + lo) * 1024 + kt * 32 + hi * 8);
#pragma unroll
      for (int j = 0; j < 8; ++j) {
        float qv = bf2f((unsigned short)af[fm][kt][j]);
        dp[fm] += qv * qv;
      }
    }
#pragma unroll
  for (int fm = 0; fm < 2; ++fm) {
    dp[fm] += __shfl_xor(dp[fm], 16);
    dp[fm] += __shfl_xor(dp[fm], 32);
  }

  float np[2][4] = {{0.f, 0.f, 0.f, 0.f}, {0.f, 0.f, 0.f, 0.f}};
#pragma unroll
  for (int hf = 0; hf < 2; ++hf) {
    f32x4 accf[2][8];
#pragma unroll
    for (int fm = 0; fm < 2; ++fm)
#pragma unroll
      for (int fn = 0; fn < 8; ++fn) accf[fm][fn] = (f32x4){0.f, 0.f, 0.f, 0.f};
#pragma unroll
    for (int fn = 0; fn < 8; ++fn) {
      int f = (hf * 8 + fn) * 16 + lo;
      short8 pb0 = *reinterpret_cast<const short8*>(PT + (size_t)f * 64 + hi * 8);
      short8 pb1 = *reinterpret_cast<const short8*>(PT + (size_t)f * 64 + 32 + hi * 8);
      accf[0][fn] = MFMA16(af[0][0], pb0, accf[0][fn], 0, 0, 0);
      accf[0][fn] = MFMA16(af[0][1], pb1, accf[0][fn], 0, 0, 0);
      accf[1][fn] = MFMA16(af[1][0], pb0, accf[1][fn], 0, 0, 0);
      accf[1][fn] = MFMA16(af[1][1], pb1, accf[1][fn], 0, 0, 0);
    }
#pragma unroll
    for (int fm = 0; fm < 2; ++fm)
#pragma unroll
      for (int fn = 0; fn < 8; ++fn)
#pragma unroll
        for (int j = 0; j < 4; ++j) {
          float dg = __shfl(dp[fm], hi * 4 + j);
          float v = 0.125f *
                    (__expf(0.35355339059327373f * accf[fm][fn][j] - 0.0625f * dg) + 1e-6f);
          np[fm][j] += v * ksr[hf * 8 + fn];
          int row = r0 + fm * 16 + hi * 4 + j;
          int f = (hf * 8 + fn) * 16 + lo;
          int byt = (row * 512 + f * 2) ^ ((row & 7) << 4);
          *reinterpret_cast<unsigned short*>(reinterpret_cast<char*>(qp) + byt) = f2bf(v);
        }
  }
#pragma unroll
  for (int fm = 0; fm < 2; ++fm)
#pragma unroll
    for (int j = 0; j < 4; ++j) {
      np[fm][j] += __shfl_xor(np[fm][j], 1);
      np[fm][j] += __shfl_xor(np[fm][j], 2);
      np[fm][j] += __shfl_xor(np[fm][j], 4);
      np[fm][j] += __shfl_xor(np[fm][j], 8);
    }
  f32x4 acco[2][4];
#pragma unroll
  for (int fm = 0; fm < 2; ++fm)
#pragma unroll
    for (int fn = 0; fn < 4; ++fn) acco[fm][fn] = (f32x4){0.f, 0.f, 0.f, 0.f};
#pragma unroll
  for (int kt2 = 0; kt2 < 8; ++kt2) {
    short8 a2[2], b2[4];
#pragma unroll
    for (int fm = 0; fm < 2; ++fm) {
      int row = r0 + fm * 16 + lo;
      int byt = (row * 512 + kt2 * 64 + hi * 16) ^ ((row & 7) << 4);
      a2[fm] = *reinterpret_cast<const short8*>(reinterpret_cast<char*>(qp) + byt);
    }
#pragma unroll
    for (int fn = 0; fn < 4; ++fn)
      b2[fn] = *reinterpret_cast<const short8*>(
          KVT + (size_t)(bh * 64 + fn * 16 + lo) * 256 + kt2 * 32 + hi * 8);
#pragma unroll
    for (int fm = 0; fm < 2; ++fm)
#pragma unroll
      for (int fn = 0; fn < 4; ++fn)
        acco[fm][fn] = MFMA16(a2[fm], b2[fn], acco[fm][fn], 0, 0, 0);
  }
#pragma unroll
  for (int fm = 0; fm < 2; ++fm)
#pragma unroll
    for (int j = 0; j < 4; ++j) {
      float nv = np[fm][j] + 1e-6f;
      int row = b * 4096 + t0 + r0 + fm * 16 + hi * 4 + j;
#pragma unroll
      for (int fn = 0; fn < 4; ++fn)
        Y[(size_t)row * 1024 + h * 64 + fn * 16 + lo] = f2bf(acco[fm][fn][j] / nv);
    }
}

// ---------- host ----------
extern "C" void kernel_launch(void* const* d_in, const int* in_sizes, int n_in,
                              void* d_out, int out_size, void* d_ws, size_t ws_size,
                              hipStream_t stream) {
  (void)in_sizes; (void)n_in; (void)out_size; (void)ws_size;
  const float* x    = (const float*)d_in[0];
  const float* Wq   = (const float*)d_in[2];
  const float* bq   = (const float*)d_in[3];
  const float* Wk   = (const float*)d_in[4];
  const float* bk   = (const float*)d_in[5];
  const float* Wv   = (const float*)d_in[6];
  const float* bv   = (const float*)d_in[7];
  const float* Wo   = (const float*)d_in[8];
  const float* bo   = (const float*)d_in[9];
  const float* proj = (const float*)d_in[10];
  float* out = (float*)d_out;

  constexpr size_t SZ_XB = (size_t)16384 * 1024 * 2;  // 32 MiB
  constexpr size_t SZ_W  = (size_t)1024 * 1024 * 2;   // 2 MiB
  constexpr size_t SZ_PT = (size_t)256 * 64 * 2;      // 32 KiB

  char* p = (char*)d_ws;
  size_t off = 0;
  char* a_xb  = p + off; off += SZ_XB;
  char* a_WqT = p + off; off += SZ_W;
  char* a_WkT = p + off; off += SZ_W;
  char* a_WvT = p + off; off += SZ_W;
  char* a_WoT = p + off; off += SZ_W;
  char* a_pT  = p + off; off += SZ_PT;
  char* a_qb  = p + off; off += SZ_XB;
  char* a_kb  = p + off; off += SZ_XB;
  char* a_ksp  = p + off; off += (size_t)8 * 64 * 256 * 4;       // 512 KiB
  char* a_kvT  = p + off; off += (size_t)64 * 64 * 256 * 2;      // 2 MiB
  char* a_ksum = p + off; off += (size_t)64 * 256 * 4;           // 64 KiB

  // kv parts alias xb (xb dead after QKV GEMM): 8*64*256*64*4 = 32 MiB exactly
  char* a_kvp = a_xb;
  // y aliases kb (kb dead after kv_fused)
  char* a_y = a_kb;
  // v and vT live in d_out (64 MiB exactly; fully overwritten by final GEMM)
  char* a_vb = (char*)d_out;
  char* a_vT = (char*)d_out + SZ_XB;

  dim3 tb(64, 4);

  cast_x_kernel<<<16384, 256, 0, stream>>>(x, (unsigned short*)a_xb, 16384 * 1024 / 4);
  tcast_f32_kernel<<<dim3(16, 16), tb, 0, stream>>>(Wq, (unsigned short*)a_WqT, 1024, 1024);
  tcast_f32_kernel<<<dim3(16, 16), tb, 0, stream>>>(Wk, (unsigned short*)a_WkT, 1024, 1024);
  tcast_f32_kernel<<<dim3(16, 16), tb, 0, stream>>>(Wv, (unsigned short*)a_WvT, 1024, 1024);
  tcast_f32_kernel<<<dim3(16, 16), tb, 0, stream>>>(Wo, (unsigned short*)a_WoT, 1024, 1024);
  tcast_f32_kernel<<<dim3(4, 1), tb, 0, stream>>>(proj, (unsigned short*)a_pT, 64, 256);

  gemm256_kernel<0><<<dim3(64, 4, 3), 512, 0, stream>>>(
      (unsigned short*)a_xb,
      (unsigned short*)a_WqT, (unsigned short*)a_WkT, (unsigned short*)a_WvT,
      bq, bk, bv, a_qb, a_kb, a_vb);

  t_bf16_kernel<<<dim3(16, 64, 4), tb, 0, stream>>>(
      (unsigned short*)a_vb, (unsigned short*)a_vT, 4096, 1024);

  kv_fused_kernel<<<dim3(8, 64), 256, 0, stream>>>(
      (unsigned short*)a_kb, (unsigned short*)a_pT, (unsigned short*)a_vT,
      (float*)a_kvp, (float*)a_ksp);
  kvred_kernel<<<64, 256, 0, stream>>>(
      (float*)a_kvp, (float*)a_ksp, (unsigned short*)a_kvT, (float*)a_ksum);

  qkv_fused_kernel<<<dim3(32, 64), 256, 0, stream>>>(
      (unsigned short*)a_qb, (unsigned short*)a_pT, (unsigned short*)a_kvT,
      (float*)a_ksum, (unsigned short*)a_y);

  gemm256_kernel<1><<<dim3(64, 4, 1), 512, 0, stream>>>(
      (unsigned short*)a_y,
      (unsigned short*)a_WoT, nullptr, nullptr,
      bo, nullptr, nullptr, out, nullptr, nullptr);
}